// Round 1
// baseline (4805.690 us; speedup 1.0000x reference)
//
#include <hip/hip_runtime.h>
#include <math.h>

#define L    1024
#define D    256
#define NCH  3
#define HEADS 32      // B*N
#define EDIM 112
#define BATCH 4

// ---------------- PE helper (fp64, one-time) ----------------
__device__ inline float pe_val(int l, int i, int dim) {
    int base = i & ~1;
    double expo = (double)base / (double)dim;
    double ang = (double)l / pow(10000.0, expo);
    return (i & 1) ? (float)cos(ang) : (float)sin(ang);
}

__global__ void pe_d_kernel(float* __restrict__ pe_d) {
    int idx = blockIdx.x * blockDim.x + threadIdx.x;
    if (idx >= L * D) return;
    int l = idx >> 8, i = idx & (D - 1);
    pe_d[idx] = pe_val(l, i, D);
}

__global__ void edge_kernel(const float* __restrict__ edge, float* __restrict__ out) {
    int idx = blockIdx.x * blockDim.x + threadIdx.x;
    if (idx >= BATCH * L * EDIM) return;
    int i = idx % EDIM;
    int l = (idx / EDIM) % L;
    out[idx] = edge[idx] + pe_val(l, i, EDIM);
}

// ---------------- QKV projection: C[r][e] = sum_d (theta[r][d]+pe[r%L][d]) * W[e][d]
#define BM 128
#define BNW 128
#define BK 16
__global__ __launch_bounds__(256) void qkv_kernel(
    const float* __restrict__ theta, const float* __restrict__ pe_d,
    const float* __restrict__ Wq, const float* __restrict__ Wk, const float* __restrict__ Wv,
    float* __restrict__ qb, float* __restrict__ kb, float* __restrict__ vb)
{
    __shared__ float As[BK][BM + 4];
    __shared__ float Bs[BK][BNW + 4];
    int tid = threadIdx.x;
    int tx = tid & 15, ty = tid >> 4;
    int rowBase = blockIdx.y * BM;
    int wsel = blockIdx.x >> 1;
    int eBase = (blockIdx.x & 1) * BNW;
    const float* W = (wsel == 0) ? Wq : (wsel == 1) ? Wk : Wv;
    float* Cb      = (wsel == 0) ? qb : (wsel == 1) ? kb : vb;

    float acc[8][8];
    #pragma unroll
    for (int i = 0; i < 8; i++)
        #pragma unroll
        for (int j = 0; j < 8; j++) acc[i][j] = 0.f;

    for (int k0 = 0; k0 < D; k0 += BK) {
        #pragma unroll
        for (int it = 0; it < 2; it++) {
            int f = tid + it * 256;     // 512 float4s for the A tile
            int row = f >> 2;
            int kg = (f & 3) * 4;
            int r = rowBase + row;
            float4 tv = *reinterpret_cast<const float4*>(&theta[(size_t)r * D + k0 + kg]);
            float4 pv = *reinterpret_cast<const float4*>(&pe_d[(size_t)(r & (L - 1)) * D + k0 + kg]);
            As[kg + 0][row] = tv.x + pv.x;
            As[kg + 1][row] = tv.y + pv.y;
            As[kg + 2][row] = tv.z + pv.z;
            As[kg + 3][row] = tv.w + pv.w;
        }
        #pragma unroll
        for (int it = 0; it < 2; it++) {
            int f = tid + it * 256;
            int row = f >> 2;
            int kg = (f & 3) * 4;
            float4 wv = *reinterpret_cast<const float4*>(&W[(size_t)(eBase + row) * D + k0 + kg]);
            Bs[kg + 0][row] = wv.x;
            Bs[kg + 1][row] = wv.y;
            Bs[kg + 2][row] = wv.z;
            Bs[kg + 3][row] = wv.w;
        }
        __syncthreads();
        #pragma unroll
        for (int kk = 0; kk < BK; kk++) {
            float a[8], b[8];
            #pragma unroll
            for (int i = 0; i < 8; i++) a[i] = As[kk][ty * 8 + i];
            #pragma unroll
            for (int j = 0; j < 8; j++) b[j] = Bs[kk][tx * 8 + j];
            #pragma unroll
            for (int i = 0; i < 8; i++)
                #pragma unroll
                for (int j = 0; j < 8; j++) acc[i][j] += a[i] * b[j];
        }
        __syncthreads();
    }
    #pragma unroll
    for (int i = 0; i < 8; i++) {
        int r = rowBase + ty * 8 + i;
        float* dst = &Cb[(size_t)r * D + eBase + tx * 8];
        float4 v0 = {acc[i][0], acc[i][1], acc[i][2], acc[i][3]};
        float4 v1 = {acc[i][4], acc[i][5], acc[i][6], acc[i][7]};
        *reinterpret_cast<float4*>(dst) = v0;
        *reinterpret_cast<float4*>(dst + 4) = v1;
    }
}

// ---------------- causal flash attention (fp32) ----------------
#define TQ 32
#define TK 16
#define QS 260   // padded LDS row stride (float4-aligned, +4 breaks bank aliasing)
__global__ __launch_bounds__(256) void attn_kernel(
    const float* __restrict__ qb, const float* __restrict__ kb,
    const float* __restrict__ vb, float* __restrict__ hout)
{
    __shared__ float Qs[TQ][QS];
    __shared__ float Ks[TK][QS];
    __shared__ float Ps[TQ][TK + 4];
    __shared__ float mS[TQ], lS[TQ], aS[TQ];

    int tid = threadIdx.x;
    int head = blockIdx.y;
    int qBase = blockIdx.x * TQ;
    size_t hb = (size_t)head * L * D;

    #pragma unroll
    for (int it = 0; it < 8; it++) {      // 32x256 Q tile -> LDS
        int f = tid + it * 256;
        int row = f >> 6;
        int off = (f & 63) * 4;
        float4 v = *reinterpret_cast<const float4*>(&qb[hb + (size_t)(qBase + row) * D + off]);
        *reinterpret_cast<float4*>(&Qs[row][off]) = v;
    }
    if (tid < TQ) { mS[tid] = -INFINITY; lS[tid] = 0.f; }

    float acc[32];
    #pragma unroll
    for (int i = 0; i < 32; i++) acc[i] = 0.f;

    int q_thread = tid >> 3;            // PV: one q row, 32 cols per thread
    int dg = (tid & 7) * 32;
    int tx = tid & 15, ty = tid >> 4;   // S: rows ty*2, ty*2+1 ; col tx

    int nkt = (qBase + TQ + TK - 1) / TK;
    for (int kt = 0; kt < nkt; kt++) {
        int kBase = kt * TK;
        __syncthreads();                 // protect Ks/Ps from previous iter readers
        #pragma unroll
        for (int it = 0; it < 4; it++) { // 16x256 K tile -> LDS
            int f = tid + it * 256;
            int row = f >> 6;
            int off = (f & 63) * 4;
            float4 v = *reinterpret_cast<const float4*>(&kb[hb + (size_t)(kBase + row) * D + off]);
            *reinterpret_cast<float4*>(&Ks[row][off]) = v;
        }
        __syncthreads();

        float s0 = 0.f, s1 = 0.f;
        int qr0 = ty * 2, qr1 = qr0 + 1;
        #pragma unroll 8
        for (int dd = 0; dd < D; dd += 4) {
            float4 k4 = *reinterpret_cast<const float4*>(&Ks[tx][dd]);
            float4 a4 = *reinterpret_cast<const float4*>(&Qs[qr0][dd]);
            float4 b4 = *reinterpret_cast<const float4*>(&Qs[qr1][dd]);
            s0 += a4.x * k4.x + a4.y * k4.y + a4.z * k4.z + a4.w * k4.w;
            s1 += b4.x * k4.x + b4.y * k4.y + b4.z * k4.z + b4.w * k4.w;
        }
        int kg = kBase + tx;
        const float scale = 0.0625f;     // 1/sqrt(256)
        s0 = (kg <= qBase + qr0) ? s0 * scale : -INFINITY;
        s1 = (kg <= qBase + qr1) ? s1 * scale : -INFINITY;
        Ps[qr0][tx] = s0;
        Ps[qr1][tx] = s1;
        __syncthreads();

        if (tid < TQ) {                  // per-row online softmax bookkeeping
            int q = tid;
            float mOld = mS[q];
            float tmax = mOld;
            #pragma unroll
            for (int j = 0; j < TK; j++) tmax = fmaxf(tmax, Ps[q][j]);
            float alpha = __expf(mOld - tmax);
            float sum = 0.f;
            #pragma unroll
            for (int j = 0; j < TK; j++) {
                float p = __expf(Ps[q][j] - tmax);
                Ps[q][j] = p;
                sum += p;
            }
            lS[q] = lS[q] * alpha + sum;
            mS[q] = tmax;
            aS[q] = alpha;
        }
        __syncthreads();

        float alpha = aS[q_thread];
        #pragma unroll
        for (int i = 0; i < 32; i++) acc[i] *= alpha;
        const float* vrow = &vb[hb + (size_t)kBase * D + dg];
        #pragma unroll 4
        for (int k = 0; k < TK; k++) {
            float p = Ps[q_thread][k];
            #pragma unroll
            for (int j = 0; j < 8; j++) {
                float4 v4 = *reinterpret_cast<const float4*>(&vrow[(size_t)k * D + j * 4]);
                acc[j * 4 + 0] += p * v4.x;
                acc[j * 4 + 1] += p * v4.y;
                acc[j * 4 + 2] += p * v4.z;
                acc[j * 4 + 3] += p * v4.w;
            }
        }
    }

    float inv = 1.f / lS[q_thread];
    size_t ob = hb + (size_t)(qBase + q_thread) * D + dg;
    #pragma unroll
    for (int j = 0; j < 8; j++) {
        float4 v = {acc[j * 4] * inv, acc[j * 4 + 1] * inv,
                    acc[j * 4 + 2] * inv, acc[j * 4 + 3] * inv};
        *reinterpret_cast<float4*>(&hout[ob + j * 4]) = v;
    }
}

// ---------------- equivariant path ----------------
__global__ __launch_bounds__(64) void equiv_kernel(
    const float* __restrict__ xi, float* __restrict__ xout)
{
    __shared__ float xs[L * NCH];        // xi + pe_n for this head
    int head = blockIdx.y;
    int tid = threadIdx.x;
    const float* xh = &xi[(size_t)head * L * NCH];
    for (int idx = tid; idx < L * NCH; idx += 64) {
        int l = idx / 3, c = idx - l * 3;
        double ang = (c == 2) ? (double)l / pow(10000.0, 2.0 / 3.0) : (double)l;
        float pe = (c == 1) ? (float)cos(ang) : (float)sin(ang);
        xs[idx] = xh[idx] + pe;
    }
    __syncthreads();

    int q = blockIdx.x * 64 + tid;
    float xq0 = xs[q * 3 + 0], xq1 = xs[q * 3 + 1], xq2 = xs[q * 3 + 2];
    // pass 1: row max of squared distances over k<=q (diagonal contributes 0)
    float m = 0.f;
    for (int k = 0; k < q; k++) {
        float d0 = xq0 - xs[k * 3 + 0];
        float d1 = xq1 - xs[k * 3 + 1];
        float d2 = xq2 - xs[k * 3 + 2];
        float sq = d0 * d0 + d1 * d1 + d2 * d2;
        m = fmaxf(m, sq);
    }
    // pass 2: Z includes diagonal; numerator sums exclude it (mbeta zeroes diag)
    float Z = __expf(-m);
    float s0 = 0.f, s1 = 0.f, s2 = 0.f, sn = 0.f;
    for (int k = 0; k < q; k++) {
        float d0 = xq0 - xs[k * 3 + 0];
        float d1 = xq1 - xs[k * 3 + 1];
        float d2 = xq2 - xs[k * 3 + 2];
        float sq = d0 * d0 + d1 * d1 + d2 * d2;
        float w = __expf(sq - m);
        Z += w; sn += w;
        s0 += w * xs[k * 3 + 0];
        s1 += w * xs[k * 3 + 1];
        s2 += w * xs[k * 3 + 2];
    }
    float inv = 0.5f / Z;                // B_CONST folded in
    size_t ob = (size_t)head * L * NCH + (size_t)q * NCH;
    xout[ob + 0] = xq0 + inv * (s0 - sn * xq0);
    xout[ob + 1] = xq1 + inv * (s1 - sn * xq1);
    xout[ob + 2] = xq2 + inv * (s2 - sn * xq2);
}

extern "C" void kernel_launch(void* const* d_in, const int* in_sizes, int n_in,
                              void* d_out, int out_size, void* d_ws, size_t ws_size,
                              hipStream_t stream)
{
    (void)in_sizes; (void)n_in; (void)out_size; (void)ws_size;
    const float* theta = (const float*)d_in[0];
    const float* xi    = (const float*)d_in[1];
    const float* edge  = (const float*)d_in[2];
    const float* Wq    = (const float*)d_in[3];
    const float* Wk    = (const float*)d_in[4];
    const float* Wv    = (const float*)d_in[5];

    float* out  = (float*)d_out;
    float* hout = out;                          // 4*8*1024*256
    float* xout = out + 8388608;                // 4*8*1024*3
    float* eout = out + 8388608 + 98304;        // 4*1024*112

    float* ws   = (float*)d_ws;
    float* qb   = ws;                            // 8388608 floats
    float* kb   = ws + 8388608;
    float* vb   = ws + 16777216;
    float* pe_d = ws + 25165824;                 // 1024*256

    pe_d_kernel<<<(L * D + 255) / 256, 256, 0, stream>>>(pe_d);
    edge_kernel<<<(BATCH * L * EDIM + 255) / 256, 256, 0, stream>>>(edge, eout);
    equiv_kernel<<<dim3(L / 64, HEADS), 64, 0, stream>>>(xi, xout);
    qkv_kernel<<<dim3(6, 256), 256, 0, stream>>>(theta, pe_d, Wq, Wk, Wv, qb, kb, vb);
    attn_kernel<<<dim3(L / TQ, HEADS), 256, 0, stream>>>(qb, kb, vb, hout);
}

// Round 2
// 560.165 us; speedup vs baseline: 8.5791x; 8.5791x over previous
//
#include <hip/hip_runtime.h>
#include <math.h>

#define L    1024
#define D    256
#define NCH  3
#define HEADS 32      // B*N
#define EDIM 112
#define BATCH 4

typedef __bf16 bf8_t __attribute__((ext_vector_type(8)));
typedef float  f4_t  __attribute__((ext_vector_type(4)));

// RNE float->bf16 (bit-exact with np/jax rounding for normal values)
__device__ inline unsigned short f2bf(float x) {
    unsigned u = __float_as_uint(x);
    u += 0x7FFFu + ((u >> 16) & 1u);
    return (unsigned short)(u >> 16);
}
__device__ inline float bf2f(unsigned short h) {
    return __uint_as_float(((unsigned)h) << 16);
}

// ---------------- PE helper (fp64, one-time) ----------------
__device__ inline float pe_val(int l, int i, int dim) {
    int base = i & ~1;
    double expo = (double)base / (double)dim;
    double ang = (double)l / pow(10000.0, expo);
    return (i & 1) ? (float)cos(ang) : (float)sin(ang);
}

__global__ void pe_d_kernel(float* __restrict__ pe_d) {
    int idx = blockIdx.x * blockDim.x + threadIdx.x;
    if (idx >= L * D) return;
    int l = idx >> 8, i = idx & (D - 1);
    pe_d[idx] = pe_val(l, i, D);
}

__global__ void edge_kernel(const float* __restrict__ edge, float* __restrict__ out) {
    int idx = blockIdx.x * blockDim.x + threadIdx.x;
    if (idx >= BATCH * L * EDIM) return;
    int i = idx % EDIM;
    int l = (idx / EDIM) % L;
    out[idx] = edge[idx] + pe_val(l, i, EDIM);
}

// ---------------- QKV projection (fp32 compute), bf16 hi/lo epilogue -------
#define BM 128
#define BNW 128
#define BK 16
__global__ __launch_bounds__(256) void qkv_kernel(
    const float* __restrict__ theta, const float* __restrict__ pe_d,
    const float* __restrict__ Wq, const float* __restrict__ Wk, const float* __restrict__ Wv,
    unsigned short* __restrict__ qh, unsigned short* __restrict__ ql,
    unsigned short* __restrict__ kh, unsigned short* __restrict__ kl,
    unsigned short* __restrict__ vbh)
{
    __shared__ float As[BK][BM + 4];
    __shared__ float Bs[BK][BNW + 4];
    int tid = threadIdx.x;
    int tx = tid & 15, ty = tid >> 4;
    int rowBase = blockIdx.y * BM;
    int wsel = blockIdx.x >> 1;
    int eBase = (blockIdx.x & 1) * BNW;
    const float* W = (wsel == 0) ? Wq : (wsel == 1) ? Wk : Wv;

    float acc[8][8];
    #pragma unroll
    for (int i = 0; i < 8; i++)
        #pragma unroll
        for (int j = 0; j < 8; j++) acc[i][j] = 0.f;

    for (int k0 = 0; k0 < D; k0 += BK) {
        #pragma unroll
        for (int it = 0; it < 2; it++) {
            int f = tid + it * 256;
            int row = f >> 2;
            int kg = (f & 3) * 4;
            int r = rowBase + row;
            float4 tv = *reinterpret_cast<const float4*>(&theta[(size_t)r * D + k0 + kg]);
            float4 pv = *reinterpret_cast<const float4*>(&pe_d[(size_t)(r & (L - 1)) * D + k0 + kg]);
            As[kg + 0][row] = tv.x + pv.x;
            As[kg + 1][row] = tv.y + pv.y;
            As[kg + 2][row] = tv.z + pv.z;
            As[kg + 3][row] = tv.w + pv.w;
        }
        #pragma unroll
        for (int it = 0; it < 2; it++) {
            int f = tid + it * 256;
            int row = f >> 2;
            int kg = (f & 3) * 4;
            float4 wv = *reinterpret_cast<const float4*>(&W[(size_t)(eBase + row) * D + k0 + kg]);
            Bs[kg + 0][row] = wv.x;
            Bs[kg + 1][row] = wv.y;
            Bs[kg + 2][row] = wv.z;
            Bs[kg + 3][row] = wv.w;
        }
        __syncthreads();
        #pragma unroll
        for (int kk = 0; kk < BK; kk++) {
            float a[8], b[8];
            #pragma unroll
            for (int i = 0; i < 8; i++) a[i] = As[kk][ty * 8 + i];
            #pragma unroll
            for (int j = 0; j < 8; j++) b[j] = Bs[kk][tx * 8 + j];
            #pragma unroll
            for (int i = 0; i < 8; i++)
                #pragma unroll
                for (int j = 0; j < 8; j++) acc[i][j] += a[i] * b[j];
        }
        __syncthreads();
    }

    union { unsigned short us[8]; float4 f4; } hi, lo;
    #pragma unroll
    for (int i = 0; i < 8; i++) {
        int r = rowBase + ty * 8 + i;
        size_t off = (size_t)r * D + eBase + tx * 8;
        if (wsel == 2) {
            #pragma unroll
            for (int j = 0; j < 8; j++) hi.us[j] = f2bf(acc[i][j]);
            *reinterpret_cast<float4*>(&vbh[off]) = hi.f4;
        } else {
            float scale = (wsel == 0) ? 0.0625f : 1.0f;   // fold 1/sqrt(d) into q
            #pragma unroll
            for (int j = 0; j < 8; j++) {
                float x = acc[i][j] * scale;
                unsigned short h = f2bf(x);
                hi.us[j] = h;
                lo.us[j] = f2bf(x - bf2f(h));
            }
            unsigned short* dh = (wsel == 0) ? qh : kh;
            unsigned short* dl = (wsel == 0) ? ql : kl;
            *reinterpret_cast<float4*>(&dh[off]) = hi.f4;
            *reinterpret_cast<float4*>(&dl[off]) = lo.f4;
        }
    }
}

// ---------------- V transpose: vbh [head][key][d] -> vt [head][d][key] ------
__global__ __launch_bounds__(256) void vtrans_kernel(
    const unsigned short* __restrict__ vbh, unsigned short* __restrict__ vt)
{
    __shared__ unsigned short T[64][70];
    int t = threadIdx.x;
    int kb = blockIdx.x * 64, db = blockIdx.y * 64, head = blockIdx.z;
    #pragma unroll
    for (int p = 0; p < 2; p++) {
        int f = t + p * 256;
        int row = f >> 3, col8 = (f & 7) * 8;
        *reinterpret_cast<float4*>(&T[row][col8]) =
            *reinterpret_cast<const float4*>(&vbh[(size_t)(head * L + kb + row) * D + db + col8]);
    }
    __syncthreads();
    int d = t >> 2, c16 = (t & 3) * 16;
    union { unsigned short us[8]; float4 f4; } o0, o1;
    #pragma unroll
    for (int j = 0; j < 8; j++) o0.us[j] = T[c16 + j][d];
    #pragma unroll
    for (int j = 0; j < 8; j++) o1.us[j] = T[c16 + 8 + j][d];
    size_t off = (size_t)(head * D + db + d) * L + kb + c16;
    *reinterpret_cast<float4*>(&vt[off]) = o0.f4;
    *reinterpret_cast<float4*>(&vt[off + 8]) = o1.f4;
}

// ---------------- MFMA flash attention -------------------------------------
#define TQA 64
#define TKA 32
__global__ __launch_bounds__(256) void attn_mfma(
    const unsigned short* __restrict__ qh, const unsigned short* __restrict__ ql,
    const unsigned short* __restrict__ kh, const unsigned short* __restrict__ kl,
    const unsigned short* __restrict__ vt, float* __restrict__ hout)
{
    __shared__ unsigned short KhS[TKA][264];   // stride 264 shorts = 132 dwords ≡ 4 mod 32
    __shared__ unsigned short KlS[TKA][264];
    __shared__ unsigned short VtS[D][40];      // stride 40 shorts = 20 dwords
    __shared__ unsigned short Pb[TQA][40];

    int tid = threadIdx.x;
    int w = tid >> 6, lane = tid & 63;
    int quad = lane >> 4, l16 = lane & 15;
    int head = blockIdx.y;
    int qt = (int)gridDim.x - 1 - (int)blockIdx.x;   // biggest tiles first
    int qBase = qt * TQA;
    size_t hb = (size_t)head * L * D;

    // Q fragments (A-layout: m=lane&15 -> q row, k=quad*8+j), resident in regs
    bf8_t qfh[8], qfl[8];
    {
        int row = qBase + w * 16 + l16;
        const unsigned short* ph = qh + hb + (size_t)row * D + quad * 8;
        const unsigned short* pl = ql + hb + (size_t)row * D + quad * 8;
        #pragma unroll
        for (int c = 0; c < 8; c++) {
            qfh[c] = *reinterpret_cast<const bf8_t*>(ph + c * 32);
            qfl[c] = *reinterpret_cast<const bf8_t*>(pl + c * 32);
        }
    }

    f4_t acc[16];
    #pragma unroll
    for (int i = 0; i < 16; i++) acc[i] = (f4_t){0.f, 0.f, 0.f, 0.f};
    float mrow[4] = {-1e30f, -1e30f, -1e30f, -1e30f};
    float lrow[4] = {0.f, 0.f, 0.f, 0.f};

    int nkt = (qBase + TQA) / TKA;
    for (int kt = 0; kt < nkt; kt++) {
        int kBase = kt * TKA;
        __syncthreads();      // prev-iter readers of KhS/KlS/VtS/Pb are done
        #pragma unroll
        for (int it = 0; it < 4; it++) {
            int c = tid + it * 256;
            int key = c >> 5, col = (c & 31) * 8;
            *reinterpret_cast<float4*>(&KhS[key][col]) =
                *reinterpret_cast<const float4*>(kh + hb + (size_t)(kBase + key) * D + col);
            *reinterpret_cast<float4*>(&KlS[key][col]) =
                *reinterpret_cast<const float4*>(kl + hb + (size_t)(kBase + key) * D + col);
            int dd = c >> 2, col2 = (c & 3) * 8;
            *reinterpret_cast<float4*>(&VtS[dd][col2]) =
                *reinterpret_cast<const float4*>(vt + (size_t)(head * D + dd) * L + kBase + col2);
        }
        __syncthreads();

        // S = Qh*Kh + Ql*Kh + Qh*Kl  (split bf16 ~= fp32 scores)
        f4_t s[2];
        s[0] = (f4_t){0.f, 0.f, 0.f, 0.f};
        s[1] = (f4_t){0.f, 0.f, 0.f, 0.f};
        #pragma unroll
        for (int c = 0; c < 8; c++) {
            #pragma unroll
            for (int t = 0; t < 2; t++) {
                bf8_t bh = *reinterpret_cast<const bf8_t*>(&KhS[t * 16 + l16][c * 32 + quad * 8]);
                bf8_t bl = *reinterpret_cast<const bf8_t*>(&KlS[t * 16 + l16][c * 32 + quad * 8]);
                s[t] = __builtin_amdgcn_mfma_f32_16x16x32_bf16(qfh[c], bh, s[t], 0, 0, 0);
                s[t] = __builtin_amdgcn_mfma_f32_16x16x32_bf16(qfl[c], bh, s[t], 0, 0, 0);
                s[t] = __builtin_amdgcn_mfma_f32_16x16x32_bf16(qfh[c], bl, s[t], 0, 0, 0);
            }
        }

        // causal mask + online softmax (rows distributed: row = quad*4+r)
        int rowq = qBase + w * 16 + quad * 4;
        #pragma unroll
        for (int r = 0; r < 4; r++) {
            #pragma unroll
            for (int t = 0; t < 2; t++)
                if (kBase + t * 16 + l16 > rowq + r) s[t][r] = -1e30f;
            float tm = fmaxf(s[0][r], s[1][r]);
            tm = fmaxf(tm, __shfl_xor(tm, 1));
            tm = fmaxf(tm, __shfl_xor(tm, 2));
            tm = fmaxf(tm, __shfl_xor(tm, 4));
            tm = fmaxf(tm, __shfl_xor(tm, 8));
            float mnew = fmaxf(mrow[r], tm);
            float alpha = __expf(mrow[r] - mnew);
            mrow[r] = mnew;
            float p0 = __expf(s[0][r] - mnew);
            float p1 = __expf(s[1][r] - mnew);
            float ts = p0 + p1;
            ts += __shfl_xor(ts, 1);
            ts += __shfl_xor(ts, 2);
            ts += __shfl_xor(ts, 4);
            ts += __shfl_xor(ts, 8);
            lrow[r] = lrow[r] * alpha + ts;
            #pragma unroll
            for (int dt = 0; dt < 16; dt++) acc[dt][r] *= alpha;
            Pb[w * 16 + quad * 4 + r][l16]      = f2bf(p0);
            Pb[w * 16 + quad * 4 + r][16 + l16] = f2bf(p1);
        }
        __syncthreads();

        // O += P * V  (P in A-layout from LDS, Vt rows give B-operand n=d)
        bf8_t pa = *reinterpret_cast<const bf8_t*>(&Pb[w * 16 + l16][quad * 8]);
        #pragma unroll
        for (int dt = 0; dt < 16; dt++) {
            bf8_t bv = *reinterpret_cast<const bf8_t*>(&VtS[dt * 16 + l16][quad * 8]);
            acc[dt] = __builtin_amdgcn_mfma_f32_16x16x32_bf16(pa, bv, acc[dt], 0, 0, 0);
        }
    }

    #pragma unroll
    for (int r = 0; r < 4; r++) {
        float inv = 1.f / lrow[r];
        int row = qBase + w * 16 + quad * 4 + r;
        float* dst = hout + hb + (size_t)row * D + l16;
        #pragma unroll
        for (int dt = 0; dt < 16; dt++) dst[dt * 16] = acc[dt][r] * inv;
    }
}

// ---------------- equivariant path ----------------
__global__ __launch_bounds__(64) void equiv_kernel(
    const float* __restrict__ xi, float* __restrict__ xout)
{
    __shared__ float xs[L * NCH];
    int head = blockIdx.y;
    int tid = threadIdx.x;
    const float* xh = &xi[(size_t)head * L * NCH];
    for (int idx = tid; idx < L * NCH; idx += 64) {
        int l = idx / 3, c = idx - l * 3;
        double ang = (c == 2) ? (double)l / pow(10000.0, 2.0 / 3.0) : (double)l;
        float pe = (c == 1) ? (float)cos(ang) : (float)sin(ang);
        xs[idx] = xh[idx] + pe;
    }
    __syncthreads();

    int q = blockIdx.x * 64 + tid;
    float xq0 = xs[q * 3 + 0], xq1 = xs[q * 3 + 1], xq2 = xs[q * 3 + 2];
    float m = 0.f;
    for (int k = 0; k < q; k++) {
        float d0 = xq0 - xs[k * 3 + 0];
        float d1 = xq1 - xs[k * 3 + 1];
        float d2 = xq2 - xs[k * 3 + 2];
        float sq = d0 * d0 + d1 * d1 + d2 * d2;
        m = fmaxf(m, sq);
    }
    float Z = __expf(-m);
    float s0 = 0.f, s1 = 0.f, s2 = 0.f, sn = 0.f;
    for (int k = 0; k < q; k++) {
        float d0 = xq0 - xs[k * 3 + 0];
        float d1 = xq1 - xs[k * 3 + 1];
        float d2 = xq2 - xs[k * 3 + 2];
        float sq = d0 * d0 + d1 * d1 + d2 * d2;
        float w = __expf(sq - m);
        Z += w; sn += w;
        s0 += w * xs[k * 3 + 0];
        s1 += w * xs[k * 3 + 1];
        s2 += w * xs[k * 3 + 2];
    }
    float inv = 0.5f / Z;
    size_t ob = (size_t)head * L * NCH + (size_t)q * NCH;
    xout[ob + 0] = xq0 + inv * (s0 - sn * xq0);
    xout[ob + 1] = xq1 + inv * (s1 - sn * xq1);
    xout[ob + 2] = xq2 + inv * (s2 - sn * xq2);
}

extern "C" void kernel_launch(void* const* d_in, const int* in_sizes, int n_in,
                              void* d_out, int out_size, void* d_ws, size_t ws_size,
                              hipStream_t stream)
{
    (void)in_sizes; (void)n_in; (void)out_size; (void)ws_size;
    const float* theta = (const float*)d_in[0];
    const float* xi    = (const float*)d_in[1];
    const float* edge  = (const float*)d_in[2];
    const float* Wq    = (const float*)d_in[3];
    const float* Wk    = (const float*)d_in[4];
    const float* Wv    = (const float*)d_in[5];

    float* out  = (float*)d_out;
    float* hout = out;                          // 4*8*1024*256
    float* xout = out + 8388608;                // 4*8*1024*3
    float* eout = out + 8388608 + 98304;        // 4*1024*112

    const size_t NE = 8388608;                  // elements per [head][L][D] buffer
    unsigned short* base = (unsigned short*)d_ws;
    unsigned short* qh  = base;
    unsigned short* ql  = base + NE;
    unsigned short* kh  = base + 2 * NE;
    unsigned short* kl  = base + 3 * NE;
    unsigned short* vbh = base + 4 * NE;
    unsigned short* vt  = base + 5 * NE;
    float* pe_d = (float*)(base + 6 * NE);      // 1024*256 floats

    pe_d_kernel<<<(L * D + 255) / 256, 256, 0, stream>>>(pe_d);
    edge_kernel<<<(BATCH * L * EDIM + 255) / 256, 256, 0, stream>>>(edge, eout);
    equiv_kernel<<<dim3(L / 64, HEADS), 64, 0, stream>>>(xi, xout);
    qkv_kernel<<<dim3(6, 256), 256, 0, stream>>>(theta, pe_d, Wq, Wk, Wv,
                                                 qh, ql, kh, kl, vbh);
    vtrans_kernel<<<dim3(L / 64, D / 64, HEADS), 256, 0, stream>>>(vbh, vt);
    attn_mfma<<<dim3(L / TQA, HEADS), 256, 0, stream>>>(qh, ql, kh, kl, vt, hout);
}

// Round 3
// 312.530 us; speedup vs baseline: 15.3767x; 1.7924x over previous
//
#include <hip/hip_runtime.h>
#include <math.h>

#define L    1024
#define D    256
#define NCH  3
#define HEADS 32      // B*N
#define EDIM 112
#define BATCH 4

typedef __bf16 bf8_t __attribute__((ext_vector_type(8)));
typedef float  f4_t  __attribute__((ext_vector_type(4)));

// RNE float->bf16
__device__ inline unsigned short f2bf(float x) {
    unsigned u = __float_as_uint(x);
    u += 0x7FFFu + ((u >> 16) & 1u);
    return (unsigned short)(u >> 16);
}
__device__ inline float bf2f(unsigned short h) {
    return __uint_as_float(((unsigned)h) << 16);
}

// ---------------- PE kernels (fp32; err ~1e-5 vs threshold 0.1) ------------
__global__ void pe_d_kernel(float* __restrict__ pe_d) {
    int idx = blockIdx.x * blockDim.x + threadIdx.x;
    if (idx >= L * D) return;
    int l = idx >> 8, i = idx & (D - 1);
    float expo = (float)(i & ~1) * (1.0f / (float)D);
    float ang = (float)l * __powf(10000.0f, -expo);
    pe_d[idx] = (i & 1) ? cosf(ang) : sinf(ang);
}

__global__ void edge_kernel(const float* __restrict__ edge, float* __restrict__ out) {
    int idx = blockIdx.x * blockDim.x + threadIdx.x;
    if (idx >= BATCH * L * EDIM) return;
    int i = idx % EDIM;
    int l = (idx / EDIM) % L;
    float expo = (float)(i & ~1) * (1.0f / (float)EDIM);
    float ang = (float)l * __powf(10000.0f, -expo);
    out[idx] = edge[idx] + ((i & 1) ? cosf(ang) : sinf(ang));
}

// ---------------- QKV projection via split-bf16 MFMA -----------------------
// C[r][e] = sum_d (theta[r][d]+pe[r%L][d]) * W[e][d]; 3-term hi/lo ~= fp32
__global__ __launch_bounds__(256) void qkv_mfma(
    const float* __restrict__ theta, const float* __restrict__ pe_d,
    const float* __restrict__ Wq, const float* __restrict__ Wk, const float* __restrict__ Wv,
    unsigned short* __restrict__ qh, unsigned short* __restrict__ ql,
    unsigned short* __restrict__ kh, unsigned short* __restrict__ kl,
    unsigned short* __restrict__ vbh)
{
    __shared__ unsigned short AsH[128][40], AsL[128][40];  // 128 rows x 32 k, stride 40
    __shared__ unsigned short BsH[128][40], BsL[128][40];

    int tid = threadIdx.x;
    int w = tid >> 6, lane = tid & 63;
    int quad = lane >> 4, l16 = lane & 15;
    int wm = (w & 1) * 64, wn = (w >> 1) * 64;
    int rowBase = blockIdx.y * 128;
    int wsel = blockIdx.x >> 1;
    int eBase = (blockIdx.x & 1) * 128;
    const float* W = (wsel == 0) ? Wq : (wsel == 1) ? Wk : Wv;

    f4_t acc[4][4];
    #pragma unroll
    for (int mi = 0; mi < 4; mi++)
        #pragma unroll
        for (int ni = 0; ni < 4; ni++) acc[mi][ni] = (f4_t){0.f, 0.f, 0.f, 0.f};

    int sr = tid >> 1;               // staging row 0..127
    int ks = (tid & 1) * 16;         // k segment 0 or 16

    for (int kt = 0; kt < 8; kt++) {
        int k0 = kt * 32;
        __syncthreads();
        // stage A = theta+pe (hi/lo) and B = W (hi/lo)
        {
            union { unsigned short us[16]; float4 f4[2]; } hi, lo;
            const float* tp = &theta[(size_t)(rowBase + sr) * D + k0 + ks];
            const float* pp = &pe_d[(size_t)((rowBase + sr) & (L - 1)) * D + k0 + ks];
            #pragma unroll
            for (int j = 0; j < 4; j++) {
                float4 tv = reinterpret_cast<const float4*>(tp)[j];
                float4 pv = reinterpret_cast<const float4*>(pp)[j];
                float xs[4] = {tv.x + pv.x, tv.y + pv.y, tv.z + pv.z, tv.w + pv.w};
                #pragma unroll
                for (int q = 0; q < 4; q++) {
                    unsigned short h = f2bf(xs[q]);
                    hi.us[j * 4 + q] = h;
                    lo.us[j * 4 + q] = f2bf(xs[q] - bf2f(h));
                }
            }
            *reinterpret_cast<float4*>(&AsH[sr][ks]) = hi.f4[0];
            *reinterpret_cast<float4*>(&AsH[sr][ks + 8]) = hi.f4[1];
            *reinterpret_cast<float4*>(&AsL[sr][ks]) = lo.f4[0];
            *reinterpret_cast<float4*>(&AsL[sr][ks + 8]) = lo.f4[1];

            const float* wp = &W[(size_t)(eBase + sr) * D + k0 + ks];
            #pragma unroll
            for (int j = 0; j < 4; j++) {
                float4 wv = reinterpret_cast<const float4*>(wp)[j];
                float xs[4] = {wv.x, wv.y, wv.z, wv.w};
                #pragma unroll
                for (int q = 0; q < 4; q++) {
                    unsigned short h = f2bf(xs[q]);
                    hi.us[j * 4 + q] = h;
                    lo.us[j * 4 + q] = f2bf(xs[q] - bf2f(h));
                }
            }
            *reinterpret_cast<float4*>(&BsH[sr][ks]) = hi.f4[0];
            *reinterpret_cast<float4*>(&BsH[sr][ks + 8]) = hi.f4[1];
            *reinterpret_cast<float4*>(&BsL[sr][ks]) = lo.f4[0];
            *reinterpret_cast<float4*>(&BsL[sr][ks + 8]) = lo.f4[1];
        }
        __syncthreads();

        bf8_t ah[4], al[4];
        #pragma unroll
        for (int mi = 0; mi < 4; mi++) {
            ah[mi] = *reinterpret_cast<const bf8_t*>(&AsH[wm + mi * 16 + l16][quad * 8]);
            al[mi] = *reinterpret_cast<const bf8_t*>(&AsL[wm + mi * 16 + l16][quad * 8]);
        }
        #pragma unroll
        for (int ni = 0; ni < 4; ni++) {
            bf8_t bh = *reinterpret_cast<const bf8_t*>(&BsH[wn + ni * 16 + l16][quad * 8]);
            bf8_t bl = *reinterpret_cast<const bf8_t*>(&BsL[wn + ni * 16 + l16][quad * 8]);
            #pragma unroll
            for (int mi = 0; mi < 4; mi++) {
                acc[mi][ni] = __builtin_amdgcn_mfma_f32_16x16x32_bf16(ah[mi], bh, acc[mi][ni], 0, 0, 0);
                acc[mi][ni] = __builtin_amdgcn_mfma_f32_16x16x32_bf16(al[mi], bh, acc[mi][ni], 0, 0, 0);
                acc[mi][ni] = __builtin_amdgcn_mfma_f32_16x16x32_bf16(ah[mi], bl, acc[mi][ni], 0, 0, 0);
            }
        }
    }

    float scale = (wsel == 0) ? 0.0625f : 1.0f;   // fold 1/sqrt(d) into q
    #pragma unroll
    for (int mi = 0; mi < 4; mi++) {
        #pragma unroll
        for (int reg = 0; reg < 4; reg++) {
            size_t r = rowBase + wm + mi * 16 + quad * 4 + reg;
            #pragma unroll
            for (int ni = 0; ni < 4; ni++) {
                int e = eBase + wn + ni * 16 + l16;
                float x = acc[mi][ni][reg];
                if (wsel == 2) {
                    vbh[r * D + e] = f2bf(x);
                } else {
                    x *= scale;
                    unsigned short h = f2bf(x);
                    unsigned short lo = f2bf(x - bf2f(h));
                    if (wsel == 0) { qh[r * D + e] = h; ql[r * D + e] = lo; }
                    else           { kh[r * D + e] = h; kl[r * D + e] = lo; }
                }
            }
        }
    }
}

// ---------------- V transpose: vbh [head][key][d] -> vt [head][d][key] ------
__global__ __launch_bounds__(256) void vtrans_kernel(
    const unsigned short* __restrict__ vbh, unsigned short* __restrict__ vt)
{
    __shared__ unsigned short T[64][70];
    int t = threadIdx.x;
    int kb = blockIdx.x * 64, db = blockIdx.y * 64, head = blockIdx.z;
    #pragma unroll
    for (int p = 0; p < 2; p++) {
        int f = t + p * 256;
        int row = f >> 3, col8 = (f & 7) * 8;
        *reinterpret_cast<float4*>(&T[row][col8]) =
            *reinterpret_cast<const float4*>(&vbh[(size_t)(head * L + kb + row) * D + db + col8]);
    }
    __syncthreads();
    int d = t >> 2, c16 = (t & 3) * 16;
    union { unsigned short us[8]; float4 f4; } o0, o1;
    #pragma unroll
    for (int j = 0; j < 8; j++) o0.us[j] = T[c16 + j][d];
    #pragma unroll
    for (int j = 0; j < 8; j++) o1.us[j] = T[c16 + 8 + j][d];
    size_t off = (size_t)(head * D + db + d) * L + kb + c16;
    *reinterpret_cast<float4*>(&vt[off]) = o0.f4;
    *reinterpret_cast<float4*>(&vt[off + 8]) = o1.f4;
}

// ---------------- MFMA flash attention, uniform-work qtile pairs -----------
#define TQA 64
#define TKA 32
__global__ __launch_bounds__(256) void attn_mfma(
    const unsigned short* __restrict__ qh, const unsigned short* __restrict__ ql,
    const unsigned short* __restrict__ kh, const unsigned short* __restrict__ kl,
    const unsigned short* __restrict__ vt, float* __restrict__ hout)
{
    __shared__ unsigned short KhS[TKA][264];
    __shared__ unsigned short KlS[TKA][264];
    __shared__ unsigned short VtS[D][40];
    __shared__ unsigned short Pb[TQA][40];

    int tid = threadIdx.x;
    int w = tid >> 6, lane = tid & 63;
    int quad = lane >> 4, l16 = lane & 15;
    int head = blockIdx.y;
    size_t hb = (size_t)head * L * D;

    // pair (qt, 15-qt): every block does exactly 34 kt-iterations
    #pragma unroll 1
    for (int half = 0; half < 2; half++) {
        int qt = half ? (15 - (int)blockIdx.x) : (int)blockIdx.x;
        int qBase = qt * TQA;

        bf8_t qfh[8], qfl[8];
        {
            int row = qBase + w * 16 + l16;
            const unsigned short* ph = qh + hb + (size_t)row * D + quad * 8;
            const unsigned short* pl = ql + hb + (size_t)row * D + quad * 8;
            #pragma unroll
            for (int c = 0; c < 8; c++) {
                qfh[c] = *reinterpret_cast<const bf8_t*>(ph + c * 32);
                qfl[c] = *reinterpret_cast<const bf8_t*>(pl + c * 32);
            }
        }

        f4_t acc[16];
        #pragma unroll
        for (int i = 0; i < 16; i++) acc[i] = (f4_t){0.f, 0.f, 0.f, 0.f};
        float mrow[4] = {-1e30f, -1e30f, -1e30f, -1e30f};
        float lrow[4] = {0.f, 0.f, 0.f, 0.f};

        int nkt = (qBase + TQA) / TKA;
        for (int kt = 0; kt < nkt; kt++) {
            int kBase = kt * TKA;
            __syncthreads();
            #pragma unroll
            for (int it = 0; it < 4; it++) {
                int c = tid + it * 256;
                int key = c >> 5, col = (c & 31) * 8;
                *reinterpret_cast<float4*>(&KhS[key][col]) =
                    *reinterpret_cast<const float4*>(kh + hb + (size_t)(kBase + key) * D + col);
                *reinterpret_cast<float4*>(&KlS[key][col]) =
                    *reinterpret_cast<const float4*>(kl + hb + (size_t)(kBase + key) * D + col);
                int dd = c >> 2, col2 = (c & 3) * 8;
                *reinterpret_cast<float4*>(&VtS[dd][col2]) =
                    *reinterpret_cast<const float4*>(vt + (size_t)(head * D + dd) * L + kBase + col2);
            }
            __syncthreads();

            f4_t s[2];
            s[0] = (f4_t){0.f, 0.f, 0.f, 0.f};
            s[1] = (f4_t){0.f, 0.f, 0.f, 0.f};
            #pragma unroll
            for (int c = 0; c < 8; c++) {
                #pragma unroll
                for (int t = 0; t < 2; t++) {
                    bf8_t bh = *reinterpret_cast<const bf8_t*>(&KhS[t * 16 + l16][c * 32 + quad * 8]);
                    bf8_t bl = *reinterpret_cast<const bf8_t*>(&KlS[t * 16 + l16][c * 32 + quad * 8]);
                    s[t] = __builtin_amdgcn_mfma_f32_16x16x32_bf16(qfh[c], bh, s[t], 0, 0, 0);
                    s[t] = __builtin_amdgcn_mfma_f32_16x16x32_bf16(qfl[c], bh, s[t], 0, 0, 0);
                    s[t] = __builtin_amdgcn_mfma_f32_16x16x32_bf16(qfh[c], bl, s[t], 0, 0, 0);
                }
            }

            int rowq = qBase + w * 16 + quad * 4;
            #pragma unroll
            for (int r = 0; r < 4; r++) {
                #pragma unroll
                for (int t = 0; t < 2; t++)
                    if (kBase + t * 16 + l16 > rowq + r) s[t][r] = -1e30f;
                float tm = fmaxf(s[0][r], s[1][r]);
                tm = fmaxf(tm, __shfl_xor(tm, 1));
                tm = fmaxf(tm, __shfl_xor(tm, 2));
                tm = fmaxf(tm, __shfl_xor(tm, 4));
                tm = fmaxf(tm, __shfl_xor(tm, 8));
                float mnew = fmaxf(mrow[r], tm);
                float alpha = __expf(mrow[r] - mnew);
                mrow[r] = mnew;
                float p0 = __expf(s[0][r] - mnew);
                float p1 = __expf(s[1][r] - mnew);
                float ts = p0 + p1;
                ts += __shfl_xor(ts, 1);
                ts += __shfl_xor(ts, 2);
                ts += __shfl_xor(ts, 4);
                ts += __shfl_xor(ts, 8);
                lrow[r] = lrow[r] * alpha + ts;
                #pragma unroll
                for (int dt = 0; dt < 16; dt++) acc[dt][r] *= alpha;
                Pb[w * 16 + quad * 4 + r][l16]      = f2bf(p0);
                Pb[w * 16 + quad * 4 + r][16 + l16] = f2bf(p1);
            }
            __syncthreads();

            bf8_t pa = *reinterpret_cast<const bf8_t*>(&Pb[w * 16 + l16][quad * 8]);
            #pragma unroll
            for (int dt = 0; dt < 16; dt++) {
                bf8_t bv = *reinterpret_cast<const bf8_t*>(&VtS[dt * 16 + l16][quad * 8]);
                acc[dt] = __builtin_amdgcn_mfma_f32_16x16x32_bf16(pa, bv, acc[dt], 0, 0, 0);
            }
        }

        #pragma unroll
        for (int r = 0; r < 4; r++) {
            float inv = 1.f / lrow[r];
            int row = qBase + w * 16 + quad * 4 + r;
            float* dst = hout + hb + (size_t)row * D + l16;
            #pragma unroll
            for (int dt = 0; dt < 16; dt++) dst[dt * 16] = acc[dt][r] * inv;
        }
    }
}

// ---------------- equivariant path: one wave per q row ---------------------
__global__ __launch_bounds__(256) void equiv_kernel(
    const float* __restrict__ xi, float* __restrict__ xout)
{
    __shared__ float xs[L * NCH];
    int head = blockIdx.y;
    int tid = threadIdx.x;
    const float* xh = &xi[(size_t)head * L * NCH];
    for (int idx = tid; idx < L * NCH; idx += 256) {
        int l = idx / 3, c = idx - l * 3;
        float ang = (c == 2) ? (float)l * 0.0021544347f : (float)l;  // 10000^(-2/3)
        float pe = (c == 1) ? cosf(ang) : sinf(ang);
        xs[idx] = xh[idx] + pe;
    }
    __syncthreads();

    int w = tid >> 6, lane = tid & 63;
    int q = blockIdx.x * 4 + w;
    float xq0 = xs[q * 3 + 0], xq1 = xs[q * 3 + 1], xq2 = xs[q * 3 + 2];

    float m = 0.f;                        // diag sq = 0 included
    for (int k = lane; k < q; k += 64) {
        float d0 = xq0 - xs[k * 3 + 0];
        float d1 = xq1 - xs[k * 3 + 1];
        float d2 = xq2 - xs[k * 3 + 2];
        m = fmaxf(m, d0 * d0 + d1 * d1 + d2 * d2);
    }
    #pragma unroll
    for (int off = 1; off < 64; off <<= 1) m = fmaxf(m, __shfl_xor(m, off));

    float s0 = 0.f, s1 = 0.f, s2 = 0.f, sn = 0.f;
    for (int k = lane; k < q; k += 64) {
        float d0 = xq0 - xs[k * 3 + 0];
        float d1 = xq1 - xs[k * 3 + 1];
        float d2 = xq2 - xs[k * 3 + 2];
        float wgt = __expf(d0 * d0 + d1 * d1 + d2 * d2 - m);
        sn += wgt;
        s0 += wgt * xs[k * 3 + 0];
        s1 += wgt * xs[k * 3 + 1];
        s2 += wgt * xs[k * 3 + 2];
    }
    #pragma unroll
    for (int off = 1; off < 64; off <<= 1) {
        sn += __shfl_xor(sn, off);
        s0 += __shfl_xor(s0, off);
        s1 += __shfl_xor(s1, off);
        s2 += __shfl_xor(s2, off);
    }
    float Z = sn + __expf(-m);            // diagonal contributes exp(0-m)
    float inv = 0.5f / Z;
    if (lane == 0) {
        size_t ob = (size_t)head * L * NCH + (size_t)q * NCH;
        xout[ob + 0] = xq0 + inv * (s0 - sn * xq0);
        xout[ob + 1] = xq1 + inv * (s1 - sn * xq1);
        xout[ob + 2] = xq2 + inv * (s2 - sn * xq2);
    }
}

extern "C" void kernel_launch(void* const* d_in, const int* in_sizes, int n_in,
                              void* d_out, int out_size, void* d_ws, size_t ws_size,
                              hipStream_t stream)
{
    (void)in_sizes; (void)n_in; (void)out_size; (void)ws_size;
    const float* theta = (const float*)d_in[0];
    const float* xi    = (const float*)d_in[1];
    const float* edge  = (const float*)d_in[2];
    const float* Wq    = (const float*)d_in[3];
    const float* Wk    = (const float*)d_in[4];
    const float* Wv    = (const float*)d_in[5];

    float* out  = (float*)d_out;
    float* hout = out;
    float* xout = out + 8388608;
    float* eout = out + 8388608 + 98304;

    const size_t NE = 8388608;
    unsigned short* base = (unsigned short*)d_ws;
    unsigned short* qh  = base;
    unsigned short* ql  = base + NE;
    unsigned short* kh  = base + 2 * NE;
    unsigned short* kl  = base + 3 * NE;
    unsigned short* vbh = base + 4 * NE;
    unsigned short* vt  = base + 5 * NE;
    float* pe_d = (float*)(base + 6 * NE);

    pe_d_kernel<<<(L * D + 255) / 256, 256, 0, stream>>>(pe_d);
    edge_kernel<<<(BATCH * L * EDIM + 255) / 256, 256, 0, stream>>>(edge, eout);
    equiv_kernel<<<dim3(L / 4, HEADS), 256, 0, stream>>>(xi, xout);
    qkv_mfma<<<dim3(6, 256), 256, 0, stream>>>(theta, pe_d, Wq, Wk, Wv,
                                               qh, ql, kh, kl, vbh);
    vtrans_kernel<<<dim3(L / 64, D / 64, HEADS), 256, 0, stream>>>(vbh, vt);
    attn_mfma<<<dim3(8, HEADS), 256, 0, stream>>>(qh, ql, kh, kl, vt, hout);
}

// Round 4
// 284.502 us; speedup vs baseline: 16.8916x; 1.0985x over previous
//
#include <hip/hip_runtime.h>
#include <math.h>

#define L    1024
#define D    256
#define NCH  3
#define HEADS 32      // B*N
#define EDIM 112
#define BATCH 4

typedef __bf16 bf8_t __attribute__((ext_vector_type(8)));
typedef float  f4_t  __attribute__((ext_vector_type(4)));

// RNE float->bf16
__device__ inline unsigned short f2bf(float x) {
    unsigned u = __float_as_uint(x);
    u += 0x7FFFu + ((u >> 16) & 1u);
    return (unsigned short)(u >> 16);
}
__device__ inline float bf2f(unsigned short h) {
    return __uint_as_float(((unsigned)h) << 16);
}

// ---------------- PE kernels (fp32; err ~1e-5 vs threshold 0.1) ------------
__global__ void pe_d_kernel(float* __restrict__ pe_d) {
    int idx = blockIdx.x * blockDim.x + threadIdx.x;
    if (idx >= L * D) return;
    int l = idx >> 8, i = idx & (D - 1);
    float expo = (float)(i & ~1) * (1.0f / (float)D);
    float ang = (float)l * __powf(10000.0f, -expo);
    pe_d[idx] = (i & 1) ? cosf(ang) : sinf(ang);
}

__global__ void edge_kernel(const float* __restrict__ edge, float* __restrict__ out) {
    int idx = blockIdx.x * blockDim.x + threadIdx.x;
    if (idx >= BATCH * L * EDIM) return;
    int i = idx % EDIM;
    int l = (idx / EDIM) % L;
    float expo = (float)(i & ~1) * (1.0f / (float)EDIM);
    float ang = (float)l * __powf(10000.0f, -expo);
    out[idx] = edge[idx] + ((i & 1) ? cosf(ang) : sinf(ang));
}

// xi + pe(n=3), computed once into xsb [32][1024][3]
__global__ void xs_kernel(const float* __restrict__ xi, float* __restrict__ xsb) {
    int idx = blockIdx.x * blockDim.x + threadIdx.x;
    if (idx >= HEADS * L * NCH) return;
    int c = idx % 3;
    int l = (idx / 3) & (L - 1);
    float ang = (c == 2) ? (float)l * 0.0021544347f : (float)l;  // 10000^(-2/3)
    float pe = (c == 1) ? cosf(ang) : sinf(ang);
    xsb[idx] = xi[idx] + pe;
}

// ---------------- QKV projection via split-bf16 MFMA (2-term) --------------
// q,k: C^T = Wh*(Xh+Xl)^T  -> packed b64 stores along e
// v:   C   = (Xh+Xl)*Wh^T  -> written tile-major vt[head][ktile32][e][key31]
__global__ __launch_bounds__(256) void qkv_mfma(
    const float* __restrict__ theta, const float* __restrict__ pe_d,
    const float* __restrict__ Wq, const float* __restrict__ Wk, const float* __restrict__ Wv,
    unsigned short* __restrict__ qh, unsigned short* __restrict__ ql,
    unsigned short* __restrict__ kh, unsigned short* __restrict__ vt)
{
    __shared__ unsigned short XsH[128][40], XsL[128][40], WsH[128][40];

    int tid = threadIdx.x;
    int w = tid >> 6, lane = tid & 63;
    int quad = lane >> 4, l16 = lane & 15;
    int aoff = (w & 1) * 64, boff = (w >> 1) * 64;
    int rowBase = blockIdx.y * 128;
    int wsel = blockIdx.x >> 1;
    int eBase = (blockIdx.x & 1) * 128;
    const float* W = (wsel == 0) ? Wq : (wsel == 1) ? Wk : Wv;

    f4_t acc[4][4];
    #pragma unroll
    for (int mi = 0; mi < 4; mi++)
        #pragma unroll
        for (int ni = 0; ni < 4; ni++) acc[mi][ni] = (f4_t){0.f, 0.f, 0.f, 0.f};

    int sr = tid >> 1;
    int ks = (tid & 1) * 16;

    for (int kt = 0; kt < 8; kt++) {
        int k0 = kt * 32 + ks;
        __syncthreads();
        {
            union { unsigned short us[16]; float4 f4[2]; } hi, lo;
            const float* tp = &theta[(size_t)(rowBase + sr) * D + k0];
            const float* pp = &pe_d[(size_t)((rowBase + sr) & (L - 1)) * D + k0];
            #pragma unroll
            for (int j = 0; j < 4; j++) {
                float4 tv = reinterpret_cast<const float4*>(tp)[j];
                float4 pv = reinterpret_cast<const float4*>(pp)[j];
                float xs[4] = {tv.x + pv.x, tv.y + pv.y, tv.z + pv.z, tv.w + pv.w};
                #pragma unroll
                for (int q = 0; q < 4; q++) {
                    unsigned short h = f2bf(xs[q]);
                    hi.us[j * 4 + q] = h;
                    lo.us[j * 4 + q] = f2bf(xs[q] - bf2f(h));
                }
            }
            *reinterpret_cast<float4*>(&XsH[sr][ks]) = hi.f4[0];
            *reinterpret_cast<float4*>(&XsH[sr][ks + 8]) = hi.f4[1];
            *reinterpret_cast<float4*>(&XsL[sr][ks]) = lo.f4[0];
            *reinterpret_cast<float4*>(&XsL[sr][ks + 8]) = lo.f4[1];

            const float* wp = &W[(size_t)(eBase + sr) * D + k0];
            #pragma unroll
            for (int j = 0; j < 4; j++) {
                float4 wv = reinterpret_cast<const float4*>(wp)[j];
                float xs[4] = {wv.x, wv.y, wv.z, wv.w};
                #pragma unroll
                for (int q = 0; q < 4; q++) hi.us[j * 4 + q] = f2bf(xs[q]);
            }
            *reinterpret_cast<float4*>(&WsH[sr][ks]) = hi.f4[0];
            *reinterpret_cast<float4*>(&WsH[sr][ks + 8]) = hi.f4[1];
        }
        __syncthreads();

        if (wsel < 2) {
            bf8_t aw[4];
            #pragma unroll
            for (int mi = 0; mi < 4; mi++)
                aw[mi] = *reinterpret_cast<const bf8_t*>(&WsH[aoff + mi * 16 + l16][quad * 8]);
            #pragma unroll
            for (int ni = 0; ni < 4; ni++) {
                bf8_t bxh = *reinterpret_cast<const bf8_t*>(&XsH[boff + ni * 16 + l16][quad * 8]);
                bf8_t bxl = *reinterpret_cast<const bf8_t*>(&XsL[boff + ni * 16 + l16][quad * 8]);
                #pragma unroll
                for (int mi = 0; mi < 4; mi++) {
                    acc[mi][ni] = __builtin_amdgcn_mfma_f32_16x16x32_bf16(aw[mi], bxh, acc[mi][ni], 0, 0, 0);
                    acc[mi][ni] = __builtin_amdgcn_mfma_f32_16x16x32_bf16(aw[mi], bxl, acc[mi][ni], 0, 0, 0);
                }
            }
        } else {
            bf8_t axh[4], axl[4];
            #pragma unroll
            for (int mi = 0; mi < 4; mi++) {
                axh[mi] = *reinterpret_cast<const bf8_t*>(&XsH[aoff + mi * 16 + l16][quad * 8]);
                axl[mi] = *reinterpret_cast<const bf8_t*>(&XsL[aoff + mi * 16 + l16][quad * 8]);
            }
            #pragma unroll
            for (int ni = 0; ni < 4; ni++) {
                bf8_t bw = *reinterpret_cast<const bf8_t*>(&WsH[boff + ni * 16 + l16][quad * 8]);
                #pragma unroll
                for (int mi = 0; mi < 4; mi++) {
                    acc[mi][ni] = __builtin_amdgcn_mfma_f32_16x16x32_bf16(axh[mi], bw, acc[mi][ni], 0, 0, 0);
                    acc[mi][ni] = __builtin_amdgcn_mfma_f32_16x16x32_bf16(axl[mi], bw, acc[mi][ni], 0, 0, 0);
                }
            }
        }
    }

    if (wsel < 2) {
        float scale = (wsel == 0) ? 0.0625f : 1.0f;  // fold 1/sqrt(d) into q
        unsigned short* dh = (wsel == 0) ? qh : kh;
        #pragma unroll
        for (int mi = 0; mi < 4; mi++) {
            #pragma unroll
            for (int ni = 0; ni < 4; ni++) {
                int e0 = eBase + aoff + mi * 16 + quad * 4;
                size_t row = rowBase + boff + ni * 16 + l16;
                union { unsigned short us[4]; unsigned long long u; } ph, pl;
                #pragma unroll
                for (int r = 0; r < 4; r++) {
                    float x = acc[mi][ni][r] * scale;
                    unsigned short h = f2bf(x);
                    ph.us[r] = h;
                    pl.us[r] = f2bf(x - bf2f(h));
                }
                *reinterpret_cast<unsigned long long*>(&dh[row * D + e0]) = ph.u;
                if (wsel == 0)
                    *reinterpret_cast<unsigned long long*>(&ql[row * D + e0]) = pl.u;
            }
        }
    } else {
        #pragma unroll
        for (int mi = 0; mi < 4; mi++) {
            #pragma unroll
            for (int ni = 0; ni < 4; ni++) {
                int row0 = rowBase + aoff + mi * 16 + quad * 4;
                int e = eBase + boff + ni * 16 + l16;
                int head = row0 >> 10, kb = (row0 & 1023) >> 5, kk = row0 & 31;
                union { unsigned short us[4]; unsigned long long u; } pk;
                #pragma unroll
                for (int r = 0; r < 4; r++) pk.us[r] = f2bf(acc[mi][ni][r]);
                *reinterpret_cast<unsigned long long*>(
                    &vt[((size_t)(head * 32 + kb)) * 8192 + (size_t)e * 32 + kk]) = pk.u;
            }
        }
    }
}

// ---------------- barrier-free MFMA flash attention ------------------------
// S^T = K*Q^T (A=K frags direct-global, B=Q regs); online softmax per-lane +
// 2 shuffles; P via wave-private LDS; O^T accumulated, packed float4 stores.
__global__ __launch_bounds__(256) void attn_v3(
    const unsigned short* __restrict__ qh, const unsigned short* __restrict__ ql,
    const unsigned short* __restrict__ kh, const unsigned short* __restrict__ vt,
    float* __restrict__ hout)
{
    __shared__ unsigned short Pb[4][16 * 40];
    int tid = threadIdx.x;
    int w = tid >> 6, lane = tid & 63;
    int quad = lane >> 4, l16 = lane & 15;
    int b = blockIdx.x;
    int head = ((b & 7) << 2) + (b >> 6);     // XCD-swizzle: head's 8 blocks share an XCD
    int pg = (b >> 3) & 7;
    int pi = (pg << 2) + w;                    // pair index 0..31 per head
    size_t hb = (size_t)head * (L * D);
    const unsigned short* vth = vt + (size_t)head * (32 * 8192);
    unsigned short* Pw = Pb[w];

    #pragma unroll 1
    for (int half = 0; half < 2; half++) {
        int u = half ? (63 - pi) : pi;         // 16-row unit; pair sums to 33 iters
        int q_g = u * 16 + l16;

        bf8_t qfh[8], qfl[8];
        {
            const unsigned short* ph = qh + hb + (size_t)q_g * D + quad * 8;
            const unsigned short* pl = ql + hb + (size_t)q_g * D + quad * 8;
            #pragma unroll
            for (int c = 0; c < 8; c++) {
                qfh[c] = *reinterpret_cast<const bf8_t*>(ph + c * 32);
                qfl[c] = *reinterpret_cast<const bf8_t*>(pl + c * 32);
            }
        }

        f4_t acc[16];
        #pragma unroll
        for (int i = 0; i < 16; i++) acc[i] = (f4_t){0.f, 0.f, 0.f, 0.f};
        float mrun = -1e30f, lrun = 0.f;

        int nkt = (u >> 1) + 1;
        for (int kt = 0; kt < nkt; kt++) {
            int kBase = kt * 32;

            f4_t s[2];
            #pragma unroll
            for (int t = 0; t < 2; t++) {
                s[t] = (f4_t){0.f, 0.f, 0.f, 0.f};
                const unsigned short* kp =
                    kh + hb + (size_t)(kBase + t * 16 + l16) * D + quad * 8;
                bf8_t kf[8];
                #pragma unroll
                for (int c = 0; c < 8; c++) kf[c] = *reinterpret_cast<const bf8_t*>(kp + c * 32);
                #pragma unroll
                for (int c = 0; c < 8; c++) {
                    s[t] = __builtin_amdgcn_mfma_f32_16x16x32_bf16(kf[c], qfh[c], s[t], 0, 0, 0);
                    s[t] = __builtin_amdgcn_mfma_f32_16x16x32_bf16(kf[c], qfl[c], s[t], 0, 0, 0);
                }
            }

            // V fragments issued early; vmcnt-covered by the softmax below
            const unsigned short* vp = vth + (size_t)kt * 8192 + l16 * 32 + quad * 8;
            bf8_t vf[16];
            #pragma unroll
            for (int dt = 0; dt < 16; dt++)
                vf[dt] = *reinterpret_cast<const bf8_t*>(vp + dt * 512);

            // causal mask + per-lane softmax over 8 keys, quad-pair reduce
            float pv[2][4];
            float tm = -1e30f;
            #pragma unroll
            for (int t = 0; t < 2; t++)
                #pragma unroll
                for (int r = 0; r < 4; r++) {
                    int key = kBase + t * 16 + quad * 4 + r;
                    float sv = (key <= q_g) ? s[t][r] : -1e30f;
                    s[t][r] = sv;
                    tm = fmaxf(tm, sv);
                }
            tm = fmaxf(tm, __shfl_xor(tm, 16));
            tm = fmaxf(tm, __shfl_xor(tm, 32));
            float mnew = fmaxf(mrun, tm);
            float alpha = __expf(mrun - mnew);
            mrun = mnew;
            float ts = 0.f;
            #pragma unroll
            for (int t = 0; t < 2; t++)
                #pragma unroll
                for (int r = 0; r < 4; r++) {
                    float p = __expf(s[t][r] - mnew);
                    pv[t][r] = p;
                    ts += p;
                }
            ts += __shfl_xor(ts, 16);
            ts += __shfl_xor(ts, 32);
            lrun = lrun * alpha + ts;
            #pragma unroll
            for (int dt = 0; dt < 16; dt++) acc[dt] *= alpha;

            #pragma unroll
            for (int t = 0; t < 2; t++) {
                union { unsigned short us[4]; unsigned long long u; } pk;
                #pragma unroll
                for (int r = 0; r < 4; r++) pk.us[r] = f2bf(pv[t][r]);
                *reinterpret_cast<unsigned long long*>(&Pw[l16 * 40 + t * 16 + quad * 4]) = pk.u;
            }
            asm volatile("s_waitcnt lgkmcnt(0)" ::: "memory");
            bf8_t pf = *reinterpret_cast<const bf8_t*>(&Pw[l16 * 40 + quad * 8]);
            #pragma unroll
            for (int dt = 0; dt < 16; dt++)
                acc[dt] = __builtin_amdgcn_mfma_f32_16x16x32_bf16(vf[dt], pf, acc[dt], 0, 0, 0);
        }

        float inv = 1.f / lrun;
        float* dst = hout + hb + (size_t)q_g * D + quad * 4;
        #pragma unroll
        for (int dt = 0; dt < 16; dt++) {
            float4 o = {acc[dt][0] * inv, acc[dt][1] * inv,
                        acc[dt][2] * inv, acc[dt][3] * inv};
            *reinterpret_cast<float4*>(dst + dt * 16) = o;
        }
    }
}

// ---------------- equivariant path: one wave per q row ---------------------
__global__ __launch_bounds__(256) void equiv_kernel(
    const float* __restrict__ xsb, float* __restrict__ xout)
{
    __shared__ float xs[L * NCH];
    int head = blockIdx.y;
    int tid = threadIdx.x;
    const float4* src = reinterpret_cast<const float4*>(xsb + (size_t)head * L * NCH);
    #pragma unroll
    for (int it = 0; it < 3; it++)
        reinterpret_cast<float4*>(xs)[tid + it * 256] = src[tid + it * 256];
    __syncthreads();

    int w = tid >> 6, lane = tid & 63;
    int q = blockIdx.x * 4 + w;
    float xq0 = xs[q * 3 + 0], xq1 = xs[q * 3 + 1], xq2 = xs[q * 3 + 2];

    float m = 0.f;
    for (int k = lane; k < q; k += 64) {
        float d0 = xq0 - xs[k * 3 + 0];
        float d1 = xq1 - xs[k * 3 + 1];
        float d2 = xq2 - xs[k * 3 + 2];
        m = fmaxf(m, d0 * d0 + d1 * d1 + d2 * d2);
    }
    #pragma unroll
    for (int off = 1; off < 64; off <<= 1) m = fmaxf(m, __shfl_xor(m, off));

    float s0 = 0.f, s1 = 0.f, s2 = 0.f, sn = 0.f;
    for (int k = lane; k < q; k += 64) {
        float d0 = xq0 - xs[k * 3 + 0];
        float d1 = xq1 - xs[k * 3 + 1];
        float d2 = xq2 - xs[k * 3 + 2];
        float wgt = __expf(d0 * d0 + d1 * d1 + d2 * d2 - m);
        sn += wgt;
        s0 += wgt * xs[k * 3 + 0];
        s1 += wgt * xs[k * 3 + 1];
        s2 += wgt * xs[k * 3 + 2];
    }
    #pragma unroll
    for (int off = 1; off < 64; off <<= 1) {
        sn += __shfl_xor(sn, off);
        s0 += __shfl_xor(s0, off);
        s1 += __shfl_xor(s1, off);
        s2 += __shfl_xor(s2, off);
    }
    float Z = sn + __expf(-m);
    float inv = 0.5f / Z;
    if (lane == 0) {
        size_t ob = (size_t)head * L * NCH + (size_t)q * NCH;
        xout[ob + 0] = xq0 + inv * (s0 - sn * xq0);
        xout[ob + 1] = xq1 + inv * (s1 - sn * xq1);
        xout[ob + 2] = xq2 + inv * (s2 - sn * xq2);
    }
}

extern "C" void kernel_launch(void* const* d_in, const int* in_sizes, int n_in,
                              void* d_out, int out_size, void* d_ws, size_t ws_size,
                              hipStream_t stream)
{
    (void)in_sizes; (void)n_in; (void)out_size; (void)ws_size;
    const float* theta = (const float*)d_in[0];
    const float* xi    = (const float*)d_in[1];
    const float* edge  = (const float*)d_in[2];
    const float* Wq    = (const float*)d_in[3];
    const float* Wk    = (const float*)d_in[4];
    const float* Wv    = (const float*)d_in[5];

    float* out  = (float*)d_out;
    float* hout = out;
    float* xout = out + 8388608;
    float* eout = out + 8388608 + 98304;

    const size_t NE = 8388608;
    unsigned short* base = (unsigned short*)d_ws;
    unsigned short* qh = base;
    unsigned short* ql = base + NE;
    unsigned short* kh = base + 2 * NE;
    unsigned short* vt = base + 3 * NE;
    float* pe_d = (float*)(base + 4 * NE);           // 1024*256 floats
    float* xsb  = pe_d + L * D;                       // 32*1024*3 floats

    pe_d_kernel<<<(L * D + 255) / 256, 256, 0, stream>>>(pe_d);
    edge_kernel<<<(BATCH * L * EDIM + 255) / 256, 256, 0, stream>>>(edge, eout);
    xs_kernel<<<(HEADS * L * NCH + 255) / 256, 256, 0, stream>>>(xi, xsb);
    equiv_kernel<<<dim3(L / 4, HEADS), 256, 0, stream>>>(xsb, xout);
    qkv_mfma<<<dim3(6, 256), 256, 0, stream>>>(theta, pe_d, Wq, Wk, Wv,
                                               qh, ql, kh, vt);
    attn_v3<<<256, 256, 0, stream>>>(qh, ql, kh, vt, hout);
}